// Round 14
// baseline (581.126 us; speedup 1.0000x reference)
//
#include <hip/hip_runtime.h>
#include <hip/hip_fp16.h>
#include <math.h>

#define N_NODES 50000
#define D       64
#define N_EDGES 800000
#define N_HEAD  4

typedef unsigned short ushort_t;
typedef unsigned int   uint_t;

// bf16 <-> fp32 bit helpers (RNE on pack)
__device__ __forceinline__ float bf_lo(uint_t u) {
    return __uint_as_float(u << 16);
}
__device__ __forceinline__ float bf_hi(uint_t u) {
    return __uint_as_float(u & 0xffff0000u);
}
__device__ __forceinline__ ushort_t f2bf(float f) {
    uint_t u = __float_as_uint(f);
    u += 0x7fffu + ((u >> 16) & 1u);   // round-to-nearest-even
    return (ushort_t)(u >> 16);
}

// ---------------------------------------------------------------------------
// prep: cv[e] = (col<<16) | bf16(val)  (col < 50000 fits 16 bits);
//       row_ptr[r] = lower_bound(edge_row, r) (edge_row sorted)
// ---------------------------------------------------------------------------
__global__ void prep_kernel(const int* __restrict__ edge_row,
                            const int* __restrict__ edge_col,
                            const float* __restrict__ edge_val,
                            int* __restrict__ row_ptr,
                            uint_t* __restrict__ cv) {
    const int i = blockIdx.x * blockDim.x + threadIdx.x;
    if (i < N_EDGES)
        cv[i] = ((uint_t)edge_col[i] << 16) | (uint_t)f2bf(edge_val[i]);
    if (i <= N_NODES) {
        int lo = 0, hi = N_EDGES;
        while (lo < hi) {
            int mid = (lo + hi) >> 1;
            if (edge_row[mid] < i) lo = mid + 1; else hi = mid;
        }
        row_ptr[i] = lo;
    }
}

// ---------------------------------------------------------------------------
// head-0 linear: t[n][j] = bf16( elu( sum_k (mask? x[n][k]:0)*W[j][k] + b[j] ) )
// lane j holds W[j][*] in 64 VGPRs; row data via wave-uniform scalar loads.
// ---------------------------------------------------------------------------
__global__ __launch_bounds__(256) void linear_elu_kernel(
        const float* __restrict__ in,
        const float* __restrict__ W,
        const float* __restrict__ b,
        const int*  __restrict__ et,
        ushort_t* __restrict__ t) {
    const int lane = threadIdx.x & 63;
    const int wid  = (blockIdx.x * blockDim.x + threadIdx.x) >> 6;
    const int nwav = (gridDim.x * blockDim.x) >> 6;

    float4 w4[16];
    {
        const float4* wp = (const float4*)(W + lane * D);
        #pragma unroll
        for (int i = 0; i < 16; ++i) w4[i] = wp[i];
    }
    const float* w = (const float*)w4;
    const float bj = b[lane];

    for (int row0 = wid; row0 < N_NODES; row0 += nwav) {
        const int row = __builtin_amdgcn_readfirstlane(row0);
        float acc = bj;
        if (et[row] != 0) {
            const float* rp = in + (size_t)row * D;
            #pragma unroll
            for (int k = 0; k < D; ++k)
                acc = fmaf(rp[k], w[k], acc);
        }
        const float e = (acc > 0.f) ? acc : expm1f(acc);
        t[(size_t)row * D + lane] = f2bf(e);
    }
}

// ---------------------------------------------------------------------------
// Fused spmm + next-head linear, HIGH-OCCUPANCY variant.
// W is held as fp16 in 32 VGPRs (fp16 rel err 2^-11, negligible vs the bf16
// t-table's 2^-8) so total VGPR <= 64 -> 8 waves/SIMD (32/CU), double the
// fp32-W version's bin (R11/R13: VGPR 68-72 -> 16/CU cap, 21% occupancy,
// 50 us). __launch_bounds__(256, 8) pins the allocator to the bin.
// Per row: R7's exact gather structure (chunk A clamped, chunk B
// wave-uniform, rare deg>32 tail), XOR-reduce, out (+)=, LDS row broadcast,
// fp16-W linear + ELU epilogue. Grid 2048 blocks = 8192 waves = 32/CU.
// ---------------------------------------------------------------------------
template<int FIRST, int DO_LINEAR>
__global__ __launch_bounds__(256, 8) void fused_kernel(
        const ushort_t* __restrict__ tin,   // bf16 [N][64]
        ushort_t* __restrict__ tout,        // bf16 [N][64]
        const float* __restrict__ W,        // next head's W
        const float* __restrict__ bvec,
        const uint_t* __restrict__ cv,      // (col<<16)|bf16(val)
        const int*  __restrict__ row_ptr,
        float* __restrict__ out) {
    __shared__ float rowbuf[4][64];
    const int tid   = threadIdx.x;
    const int lane  = tid & 63;
    const int wslot = tid >> 6;
    const int g     = lane >> 4;
    const int l     = lane & 15;
    const int wid   = (blockIdx.x * blockDim.x + tid) >> 6;
    const int nwav  = (gridDim.x * blockDim.x) >> 6;

    __half2 wh[32];          // W[lane][0..63] in fp16 pairs (32 VGPRs)
    float bj = 0.f;
    if (DO_LINEAR) {
        const float4* wp = (const float4*)(W + lane * D);
        #pragma unroll
        for (int i = 0; i < 16; ++i) {
            const float4 v = wp[i];
            wh[2 * i + 0] = __floats2half2_rn(v.x, v.y);
            wh[2 * i + 1] = __floats2half2_rn(v.z, v.w);
        }
        bj = bvec[lane];
    }

    for (int row0 = wid; row0 < N_NODES; row0 += nwav) {
        const int row = __builtin_amdgcn_readfirstlane(row0);
        const size_t base = (size_t)row * D + (size_t)l * 4;

        const int e0 = row_ptr[row];
        const int e1 = row_ptr[row + 1];
        const int eclamp = (e1 > 0) ? e1 - 1 : 0;
        const bool haveB = (e0 + 16) < e1;   // wave-uniform

        float4 oldo = {0.f, 0.f, 0.f, 0.f};
        if (!FIRST && g == 0) oldo = *(const float4*)(out + base);

        int   cA[4], cB[4];
        float vA[4], vB[4];
        #pragma unroll
        for (int u = 0; u < 4; ++u) {
            const int  ce = e0 + 4 * u + g;
            const bool ok = ce < e1;
            const uint_t p = cv[ok ? ce : eclamp];
            cA[u] = (int)(p >> 16);
            vA[u] = ok ? bf_lo(p) : 0.f;
        }
        if (haveB) {
            #pragma unroll
            for (int u = 0; u < 4; ++u) {
                const int  ce = e0 + 16 + 4 * u + g;
                const bool ok = ce < e1;
                const uint_t p = cv[ok ? ce : eclamp];
                cB[u] = (int)(p >> 16);
                vB[u] = ok ? bf_lo(p) : 0.f;
            }
        }

        uint2 rA[4], rB[4];
        #pragma unroll
        for (int u = 0; u < 4; ++u)
            rA[u] = *(const uint2*)(tin + (size_t)cA[u] * D + l * 4);
        if (haveB) {
            #pragma unroll
            for (int u = 0; u < 4; ++u)
                rB[u] = *(const uint2*)(tin + (size_t)cB[u] * D + l * 4);
        }

        float4 acc = {0.f, 0.f, 0.f, 0.f};
        #pragma unroll
        for (int u = 0; u < 4; ++u) {
            acc.x = fmaf(vA[u], bf_lo(rA[u].x), acc.x);
            acc.y = fmaf(vA[u], bf_hi(rA[u].x), acc.y);
            acc.z = fmaf(vA[u], bf_lo(rA[u].y), acc.z);
            acc.w = fmaf(vA[u], bf_hi(rA[u].y), acc.w);
        }
        if (haveB) {
            #pragma unroll
            for (int u = 0; u < 4; ++u) {
                acc.x = fmaf(vB[u], bf_lo(rB[u].x), acc.x);
                acc.y = fmaf(vB[u], bf_hi(rB[u].x), acc.y);
                acc.z = fmaf(vB[u], bf_lo(rB[u].y), acc.z);
                acc.w = fmaf(vB[u], bf_hi(rB[u].y), acc.w);
            }
        }
        // rare tail: deg > 32
        for (int e = e0 + 32; e < e1; e += 16) {
            #pragma unroll
            for (int u = 0; u < 4; ++u) {
                const int  ce = e + 4 * u + g;
                const bool ok = ce < e1;
                const uint_t p = cv[ok ? ce : eclamp];
                const int   c = (int)(p >> 16);
                const float v = ok ? bf_lo(p) : 0.f;
                const uint2 r = *(const uint2*)(tin + (size_t)c * D + l * 4);
                acc.x = fmaf(v, bf_lo(r.x), acc.x);
                acc.y = fmaf(v, bf_hi(r.x), acc.y);
                acc.z = fmaf(v, bf_lo(r.y), acc.z);
                acc.w = fmaf(v, bf_hi(r.y), acc.w);
            }
        }

        // reduce across the 4 groups (lane bits 4,5)
        #pragma unroll
        for (int off = 16; off < 64; off <<= 1) {
            acc.x += __shfl_xor(acc.x, off, 64);
            acc.y += __shfl_xor(acc.y, off, 64);
            acc.z += __shfl_xor(acc.z, off, 64);
            acc.w += __shfl_xor(acc.w, off, 64);
        }

        if (g == 0) {
            float4 o;
            o.x = acc.x + oldo.x; o.y = acc.y + oldo.y;
            o.z = acc.z + oldo.z; o.w = acc.w + oldo.w;
            *(float4*)(out + base) = o;
            if (DO_LINEAR)
                *(float4*)&rowbuf[wslot][l * 4] =
                    make_float4(acc.x, acc.y, acc.z, acc.w);
        }

        if (DO_LINEAR) {
            // same-wave LDS RAW: compiler inserts lgkmcnt wait (R11-proven)
            float lacc = bj;
            #pragma unroll
            for (int k = 0; k < 16; ++k) {
                const float4 r = *(const float4*)&rowbuf[wslot][k * 4];
                lacc = fmaf(r.x, __low2float(wh[2 * k + 0]), lacc);
                lacc = fmaf(r.y, __high2float(wh[2 * k + 0]), lacc);
                lacc = fmaf(r.z, __low2float(wh[2 * k + 1]), lacc);
                lacc = fmaf(r.w, __high2float(wh[2 * k + 1]), lacc);
            }
            const float eo = (lacc > 0.f) ? lacc : expm1f(lacc);
            tout[(size_t)row * D + lane] = f2bf(eo);
        }
    }
}

// ---------------------------------------------------------------------------
// head-4 spmm (no linear epilogue) — unmodified R7 structure, 1 row/wave.
// ---------------------------------------------------------------------------
__global__ __launch_bounds__(256) void spmm_kernel(
        const ushort_t* __restrict__ tin,
        const uint_t* __restrict__ cv,
        const int*   __restrict__ row_ptr,
        float* __restrict__ out) {
    const int lane = threadIdx.x & 63;
    const int g    = lane >> 4;
    const int l    = lane & 15;
    const int row0 = (blockIdx.x * blockDim.x + threadIdx.x) >> 6;
    if (row0 >= N_NODES) return;
    const int row = __builtin_amdgcn_readfirstlane(row0);

    const int e0 = row_ptr[row];
    const int e1 = row_ptr[row + 1];
    const int eclamp = (e1 > 0) ? e1 - 1 : 0;
    float4 acc = {0.f, 0.f, 0.f, 0.f};

    int   cA[4], cB[4];
    float vA[4], vB[4];
    uint2 rA[4], rB[4];
    const bool haveB = (e0 + 16) < e1;

    #pragma unroll
    for (int u = 0; u < 4; ++u) {
        const int  ce = e0 + 4 * u + g;
        const bool ok = ce < e1;
        const uint_t p = cv[ok ? ce : eclamp];
        cA[u] = (int)(p >> 16);
        vA[u] = ok ? bf_lo(p) : 0.f;
    }
    if (haveB) {
        #pragma unroll
        for (int u = 0; u < 4; ++u) {
            const int  ce = e0 + 16 + 4 * u + g;
            const bool ok = ce < e1;
            const uint_t p = cv[ok ? ce : eclamp];
            cB[u] = (int)(p >> 16);
            vB[u] = ok ? bf_lo(p) : 0.f;
        }
    }
    #pragma unroll
    for (int u = 0; u < 4; ++u)
        rA[u] = *(const uint2*)(tin + (size_t)cA[u] * D + l * 4);
    if (haveB) {
        #pragma unroll
        for (int u = 0; u < 4; ++u)
            rB[u] = *(const uint2*)(tin + (size_t)cB[u] * D + l * 4);
    }
    #pragma unroll
    for (int u = 0; u < 4; ++u) {
        acc.x = fmaf(vA[u], bf_lo(rA[u].x), acc.x);
        acc.y = fmaf(vA[u], bf_hi(rA[u].x), acc.y);
        acc.z = fmaf(vA[u], bf_lo(rA[u].y), acc.z);
        acc.w = fmaf(vA[u], bf_hi(rA[u].y), acc.w);
    }
    if (haveB) {
        #pragma unroll
        for (int u = 0; u < 4; ++u) {
            acc.x = fmaf(vB[u], bf_lo(rB[u].x), acc.x);
            acc.y = fmaf(vB[u], bf_hi(rB[u].x), acc.y);
            acc.z = fmaf(vB[u], bf_lo(rB[u].y), acc.z);
            acc.w = fmaf(vB[u], bf_hi(rB[u].y), acc.w);
        }
    }
    for (int e = e0 + 32; e < e1; e += 16) {
        #pragma unroll
        for (int u = 0; u < 4; ++u) {
            const int  ce = e + 4 * u + g;
            const bool ok = ce < e1;
            const uint_t p = cv[ok ? ce : eclamp];
            const int   c = (int)(p >> 16);
            const float v = ok ? bf_lo(p) : 0.f;
            const uint2 r = *(const uint2*)(tin + (size_t)c * D + l * 4);
            acc.x = fmaf(v, bf_lo(r.x), acc.x);
            acc.y = fmaf(v, bf_hi(r.x), acc.y);
            acc.z = fmaf(v, bf_lo(r.y), acc.z);
            acc.w = fmaf(v, bf_hi(r.y), acc.w);
        }
    }

    #pragma unroll
    for (int off = 16; off < 64; off <<= 1) {
        acc.x += __shfl_xor(acc.x, off, 64);
        acc.y += __shfl_xor(acc.y, off, 64);
        acc.z += __shfl_xor(acc.z, off, 64);
        acc.w += __shfl_xor(acc.w, off, 64);
    }

    if (g == 0) {
        const size_t base = (size_t)row * D + (size_t)l * 4;
        float4 o = *(const float4*)(out + base);
        o.x += acc.x; o.y += acc.y; o.z += acc.z; o.w += acc.w;
        *(float4*)(out + base) = o;
    }
}

// ---------------------------------------------------------------------------
extern "C" void kernel_launch(void* const* d_in, const int* in_sizes, int n_in,
                              void* d_out, int out_size, void* d_ws, size_t ws_size,
                              hipStream_t stream) {
    const float* x        = (const float*)d_in[0];  // [N, 64]
    const float* edge_val = (const float*)d_in[1];  // [E]
    const float* W        = (const float*)d_in[2];  // [4, 64, 64]
    const float* b        = (const float*)d_in[3];  // [4, 64]
    const int* edge_row   = (const int*)d_in[4];    // sorted
    const int* edge_col   = (const int*)d_in[5];
    const int* event_type = (const int*)d_in[6];    // [N] (int32 on device)
    float* out = (float*)d_out;

    // ws: cv uint32[E] | row_ptr[N+2] | tA bf16[N*64] | tB bf16[N*64]
    char* p = (char*)d_ws;
    uint_t*   cv      = (uint_t*)p;                  p += (size_t)N_EDGES * 4;
    int*      row_ptr = (int*)p;                     p += (size_t)(N_NODES + 2) * 4;
    p = (char*)(((uintptr_t)p + 15) & ~(uintptr_t)15);
    ushort_t* tA      = (ushort_t*)p;                p += (size_t)N_NODES * D * 2;
    ushort_t* tB      = (ushort_t*)p;

    prep_kernel<<<(N_EDGES + 255) / 256, 256, 0, stream>>>(
        edge_row, edge_col, edge_val, row_ptr, cv);

    // head 0 linear: x (masked) -> tA
    linear_elu_kernel<<<1024, 256, 0, stream>>>(x, W, b, event_type, tA);

    // fused: spmm(t_i) -> out ; linear_{i+1} -> t_{i+1}
    // 2048 blocks = 8192 waves = 32 waves/CU at VGPR<=64 (fp16 W tile).
    fused_kernel<1, 1><<<2048, 256, 0, stream>>>(
        tA, tB, W + 1 * D * D, b + 1 * D, cv, row_ptr, out);
    fused_kernel<0, 1><<<2048, 256, 0, stream>>>(
        tB, tA, W + 2 * D * D, b + 2 * D, cv, row_ptr, out);
    fused_kernel<0, 1><<<2048, 256, 0, stream>>>(
        tA, tB, W + 3 * D * D, b + 3 * D, cv, row_ptr, out);

    // head 4: spmm only (R7 structure, 1 row/wave)
    spmm_kernel<<<(N_NODES * 64 + 255) / 256, 256, 0, stream>>>(
        tB, cv, row_ptr, out);
}

// Round 15
// 154.068 us; speedup vs baseline: 3.7719x; 3.7719x over previous
//
#include <hip/hip_runtime.h>
#include <math.h>

#define N_NODES 50000
#define D       64
#define N_EDGES 800000
#define N_HEAD  4

typedef unsigned short ushort_t;
typedef unsigned int   uint_t;

// bf16 <-> fp32 bit helpers (RNE on pack)
__device__ __forceinline__ float bf_lo(uint_t u) {
    return __uint_as_float(u << 16);
}
__device__ __forceinline__ float bf_hi(uint_t u) {
    return __uint_as_float(u & 0xffff0000u);
}
__device__ __forceinline__ ushort_t f2bf(float f) {
    uint_t u = __float_as_uint(f);
    u += 0x7fffu + ((u >> 16) & 1u);   // round-to-nearest-even
    return (ushort_t)(u >> 16);
}

// ---------------------------------------------------------------------------
// prep: cv[e] = (col<<16) | bf16(val)  (col < 50000 fits 16 bits);
//       row_ptr[r] = lower_bound(edge_row, r) (edge_row sorted)
// ---------------------------------------------------------------------------
__global__ void prep_kernel(const int* __restrict__ edge_row,
                            const int* __restrict__ edge_col,
                            const float* __restrict__ edge_val,
                            int* __restrict__ row_ptr,
                            uint_t* __restrict__ cv) {
    const int i = blockIdx.x * blockDim.x + threadIdx.x;
    if (i < N_EDGES)
        cv[i] = ((uint_t)edge_col[i] << 16) | (uint_t)f2bf(edge_val[i]);
    if (i <= N_NODES) {
        int lo = 0, hi = N_EDGES;
        while (lo < hi) {
            int mid = (lo + hi) >> 1;
            if (edge_row[mid] < i) lo = mid + 1; else hi = mid;
        }
        row_ptr[i] = lo;
    }
}

// ---------------------------------------------------------------------------
// head-0 linear: t[n][j] = bf16( elu( sum_k (mask? x[n][k]:0)*W[j][k] + b[j] ) )
// lane j holds W[j][*] in 64 VGPRs; row data via wave-uniform scalar loads.
// ---------------------------------------------------------------------------
__global__ __launch_bounds__(256) void linear_elu_kernel(
        const float* __restrict__ in,
        const float* __restrict__ W,
        const float* __restrict__ b,
        const int*  __restrict__ et,
        ushort_t* __restrict__ t) {
    const int lane = threadIdx.x & 63;
    const int wid  = (blockIdx.x * blockDim.x + threadIdx.x) >> 6;
    const int nwav = (gridDim.x * blockDim.x) >> 6;

    float4 w4[16];
    {
        const float4* wp = (const float4*)(W + lane * D);
        #pragma unroll
        for (int i = 0; i < 16; ++i) w4[i] = wp[i];
    }
    const float* w = (const float*)w4;
    const float bj = b[lane];

    for (int row0 = wid; row0 < N_NODES; row0 += nwav) {
        const int row = __builtin_amdgcn_readfirstlane(row0);
        float acc = bj;
        if (et[row] != 0) {
            const float* rp = in + (size_t)row * D;
            #pragma unroll
            for (int k = 0; k < D; ++k)
                acc = fmaf(rp[k], w[k], acc);
        }
        const float e = (acc > 0.f) ? acc : expm1f(acc);
        t[(size_t)row * D + lane] = f2bf(e);
    }
}

// ---------------------------------------------------------------------------
// Fused spmm + next-head linear, W-IN-LDS variant.
// R11/R13: W in 64 VGPRs -> total 68-72 -> 16 waves/CU bin -> 21% occupancy.
// R14: pinning VGPR=32 -> scratch spill disaster. This round: W lives in LDS
// (16 KB/block, cooperative load once per block, transposed-float4 layout
// Wq[k/4][j][4] so lane j reads contiguous 16 B via ds_read_b128). Natural
// VGPR use ~44 -> <=64 bin -> 32 waves/CU capacity; grid 2048 blocks fills it.
// Per row: R7's exact gather structure, XOR-reduce, out (+)=, LDS row
// broadcast, LDS-W linear + ELU epilogue.
// ---------------------------------------------------------------------------
template<int FIRST>
__global__ __launch_bounds__(256) void fused_kernel(
        const ushort_t* __restrict__ tin,   // bf16 [N][64]
        ushort_t* __restrict__ tout,        // bf16 [N][64]
        const float* __restrict__ W,        // next head's W [64][64]
        const float* __restrict__ bvec,
        const uint_t* __restrict__ cv,      // (col<<16)|bf16(val)
        const int*  __restrict__ row_ptr,
        float* __restrict__ out) {
    __shared__ float wlds[16][64][4];   // Wq[kq][j][c] = W[j][4kq+c], 16 KB
    __shared__ float rowbuf[4][64];
    const int tid   = threadIdx.x;
    const int lane  = tid & 63;
    const int wslot = tid >> 6;
    const int g     = lane >> 4;
    const int l     = lane & 15;
    const int wid   = (blockIdx.x * blockDim.x + tid) >> 6;
    const int nwav  = (gridDim.x * blockDim.x) >> 6;

    // cooperative W load: coalesced global read, once per block
    for (int idx = tid; idx < D * D; idx += 256) {
        const int j = idx >> 6, k = idx & 63;
        wlds[k >> 2][j][k & 3] = W[idx];
    }
    __syncthreads();

    const float bj = bvec[lane];

    for (int row0 = wid; row0 < N_NODES; row0 += nwav) {
        const int row = __builtin_amdgcn_readfirstlane(row0);
        const size_t base = (size_t)row * D + (size_t)l * 4;

        const int e0 = row_ptr[row];
        const int e1 = row_ptr[row + 1];
        const int eclamp = (e1 > 0) ? e1 - 1 : 0;
        const bool haveB = (e0 + 16) < e1;   // wave-uniform

        float4 oldo = {0.f, 0.f, 0.f, 0.f};
        if (!FIRST && g == 0) oldo = *(const float4*)(out + base);

        // metadata (packed col|val stays in mc; decode transiently)
        uint_t mc[8];
        #pragma unroll
        for (int u = 0; u < 4; ++u) {
            const int ce = e0 + 4 * u + g;
            mc[u] = cv[(ce < e1) ? ce : eclamp];
        }
        #pragma unroll
        for (int u = 0; u < 4; ++u) {
            const int ce = e0 + 16 + 4 * u + g;
            mc[4 + u] = cv[(ce < e1 && haveB) ? ce : eclamp];
        }

        // gathers: up to 8 in flight
        uint2 rA[4], rB[4];
        #pragma unroll
        for (int u = 0; u < 4; ++u)
            rA[u] = *(const uint2*)(tin + (size_t)(mc[u] >> 16) * D + l * 4);
        if (haveB) {
            #pragma unroll
            for (int u = 0; u < 4; ++u)
                rB[u] = *(const uint2*)(tin + (size_t)(mc[4 + u] >> 16) * D + l * 4);
        }

        float4 acc = {0.f, 0.f, 0.f, 0.f};
        #pragma unroll
        for (int u = 0; u < 4; ++u) {
            const int  ce = e0 + 4 * u + g;
            const float v = (ce < e1) ? bf_lo(mc[u]) : 0.f;
            acc.x = fmaf(v, bf_lo(rA[u].x), acc.x);
            acc.y = fmaf(v, bf_hi(rA[u].x), acc.y);
            acc.z = fmaf(v, bf_lo(rA[u].y), acc.z);
            acc.w = fmaf(v, bf_hi(rA[u].y), acc.w);
        }
        if (haveB) {
            #pragma unroll
            for (int u = 0; u < 4; ++u) {
                const int  ce = e0 + 16 + 4 * u + g;
                const float v = (ce < e1) ? bf_lo(mc[4 + u]) : 0.f;
                acc.x = fmaf(v, bf_lo(rB[u].x), acc.x);
                acc.y = fmaf(v, bf_hi(rB[u].x), acc.y);
                acc.z = fmaf(v, bf_lo(rB[u].y), acc.z);
                acc.w = fmaf(v, bf_hi(rB[u].y), acc.w);
            }
        }
        // rare tail: deg > 32
        for (int e = e0 + 32; e < e1; e += 16) {
            #pragma unroll
            for (int u = 0; u < 4; ++u) {
                const int  ce = e + 4 * u + g;
                const bool ok = ce < e1;
                const uint_t p = cv[ok ? ce : eclamp];
                const float v = ok ? bf_lo(p) : 0.f;
                const uint2 r = *(const uint2*)(tin + (size_t)(p >> 16) * D + l * 4);
                acc.x = fmaf(v, bf_lo(r.x), acc.x);
                acc.y = fmaf(v, bf_hi(r.x), acc.y);
                acc.z = fmaf(v, bf_lo(r.y), acc.z);
                acc.w = fmaf(v, bf_hi(r.y), acc.w);
            }
        }

        // reduce across the 4 groups (lane bits 4,5)
        #pragma unroll
        for (int off = 16; off < 64; off <<= 1) {
            acc.x += __shfl_xor(acc.x, off, 64);
            acc.y += __shfl_xor(acc.y, off, 64);
            acc.z += __shfl_xor(acc.z, off, 64);
            acc.w += __shfl_xor(acc.w, off, 64);
        }

        if (g == 0) {
            float4 o;
            o.x = acc.x + oldo.x; o.y = acc.y + oldo.y;
            o.z = acc.z + oldo.z; o.w = acc.w + oldo.w;
            *(float4*)(out + base) = o;
            *(float4*)&rowbuf[wslot][l * 4] =
                make_float4(acc.x, acc.y, acc.z, acc.w);
        }

        // linear epilogue: same-wave LDS RAW (compiler inserts lgkmcnt wait)
        float lacc = bj;
        #pragma unroll
        for (int kq = 0; kq < 16; ++kq) {
            const float4 wv = *(const float4*)&wlds[kq][lane][0];
            const float4 r  = *(const float4*)&rowbuf[wslot][kq * 4];
            lacc = fmaf(r.x, wv.x, lacc);
            lacc = fmaf(r.y, wv.y, lacc);
            lacc = fmaf(r.z, wv.z, lacc);
            lacc = fmaf(r.w, wv.w, lacc);
        }
        const float eo = (lacc > 0.f) ? lacc : expm1f(lacc);
        tout[(size_t)row * D + lane] = f2bf(eo);
    }
}

// ---------------------------------------------------------------------------
// head-4 spmm (no linear epilogue) — unmodified R7 structure, 1 row/wave.
// ---------------------------------------------------------------------------
__global__ __launch_bounds__(256) void spmm_kernel(
        const ushort_t* __restrict__ tin,
        const uint_t* __restrict__ cv,
        const int*   __restrict__ row_ptr,
        float* __restrict__ out) {
    const int lane = threadIdx.x & 63;
    const int g    = lane >> 4;
    const int l    = lane & 15;
    const int row0 = (blockIdx.x * blockDim.x + threadIdx.x) >> 6;
    if (row0 >= N_NODES) return;
    const int row = __builtin_amdgcn_readfirstlane(row0);

    const int e0 = row_ptr[row];
    const int e1 = row_ptr[row + 1];
    const int eclamp = (e1 > 0) ? e1 - 1 : 0;
    float4 acc = {0.f, 0.f, 0.f, 0.f};

    int   cA[4], cB[4];
    float vA[4], vB[4];
    uint2 rA[4], rB[4];
    const bool haveB = (e0 + 16) < e1;

    #pragma unroll
    for (int u = 0; u < 4; ++u) {
        const int  ce = e0 + 4 * u + g;
        const bool ok = ce < e1;
        const uint_t p = cv[ok ? ce : eclamp];
        cA[u] = (int)(p >> 16);
        vA[u] = ok ? bf_lo(p) : 0.f;
    }
    if (haveB) {
        #pragma unroll
        for (int u = 0; u < 4; ++u) {
            const int  ce = e0 + 16 + 4 * u + g;
            const bool ok = ce < e1;
            const uint_t p = cv[ok ? ce : eclamp];
            cB[u] = (int)(p >> 16);
            vB[u] = ok ? bf_lo(p) : 0.f;
        }
    }
    #pragma unroll
    for (int u = 0; u < 4; ++u)
        rA[u] = *(const uint2*)(tin + (size_t)cA[u] * D + l * 4);
    if (haveB) {
        #pragma unroll
        for (int u = 0; u < 4; ++u)
            rB[u] = *(const uint2*)(tin + (size_t)cB[u] * D + l * 4);
    }
    #pragma unroll
    for (int u = 0; u < 4; ++u) {
        acc.x = fmaf(vA[u], bf_lo(rA[u].x), acc.x);
        acc.y = fmaf(vA[u], bf_hi(rA[u].x), acc.y);
        acc.z = fmaf(vA[u], bf_lo(rA[u].y), acc.z);
        acc.w = fmaf(vA[u], bf_hi(rA[u].y), acc.w);
    }
    if (haveB) {
        #pragma unroll
        for (int u = 0; u < 4; ++u) {
            acc.x = fmaf(vB[u], bf_lo(rB[u].x), acc.x);
            acc.y = fmaf(vB[u], bf_hi(rB[u].x), acc.y);
            acc.z = fmaf(vB[u], bf_lo(rB[u].y), acc.z);
            acc.w = fmaf(vB[u], bf_hi(rB[u].y), acc.w);
        }
    }
    for (int e = e0 + 32; e < e1; e += 16) {
        #pragma unroll
        for (int u = 0; u < 4; ++u) {
            const int  ce = e + 4 * u + g;
            const bool ok = ce < e1;
            const uint_t p = cv[ok ? ce : eclamp];
            const int   c = (int)(p >> 16);
            const float v = ok ? bf_lo(p) : 0.f;
            const uint2 r = *(const uint2*)(tin + (size_t)c * D + l * 4);
            acc.x = fmaf(v, bf_lo(r.x), acc.x);
            acc.y = fmaf(v, bf_hi(r.x), acc.y);
            acc.z = fmaf(v, bf_lo(r.y), acc.z);
            acc.w = fmaf(v, bf_hi(r.y), acc.w);
        }
    }

    #pragma unroll
    for (int off = 16; off < 64; off <<= 1) {
        acc.x += __shfl_xor(acc.x, off, 64);
        acc.y += __shfl_xor(acc.y, off, 64);
        acc.z += __shfl_xor(acc.z, off, 64);
        acc.w += __shfl_xor(acc.w, off, 64);
    }

    if (g == 0) {
        const size_t base = (size_t)row * D + (size_t)l * 4;
        float4 o = *(const float4*)(out + base);
        o.x += acc.x; o.y += acc.y; o.z += acc.z; o.w += acc.w;
        *(float4*)(out + base) = o;
    }
}

// ---------------------------------------------------------------------------
extern "C" void kernel_launch(void* const* d_in, const int* in_sizes, int n_in,
                              void* d_out, int out_size, void* d_ws, size_t ws_size,
                              hipStream_t stream) {
    const float* x        = (const float*)d_in[0];  // [N, 64]
    const float* edge_val = (const float*)d_in[1];  // [E]
    const float* W        = (const float*)d_in[2];  // [4, 64, 64]
    const float* b        = (const float*)d_in[3];  // [4, 64]
    const int* edge_row   = (const int*)d_in[4];    // sorted
    const int* edge_col   = (const int*)d_in[5];
    const int* event_type = (const int*)d_in[6];    // [N] (int32 on device)
    float* out = (float*)d_out;

    // ws: cv uint32[E] | row_ptr[N+2] | tA bf16[N*64] | tB bf16[N*64]
    char* p = (char*)d_ws;
    uint_t*   cv      = (uint_t*)p;                  p += (size_t)N_EDGES * 4;
    int*      row_ptr = (int*)p;                     p += (size_t)(N_NODES + 2) * 4;
    p = (char*)(((uintptr_t)p + 15) & ~(uintptr_t)15);
    ushort_t* tA      = (ushort_t*)p;                p += (size_t)N_NODES * D * 2;
    ushort_t* tB      = (ushort_t*)p;

    prep_kernel<<<(N_EDGES + 255) / 256, 256, 0, stream>>>(
        edge_row, edge_col, edge_val, row_ptr, cv);

    // head 0 linear: x (masked) -> tA
    linear_elu_kernel<<<1024, 256, 0, stream>>>(x, W, b, event_type, tA);

    // fused: spmm(t_i) -> out ; linear_{i+1} -> t_{i+1}
    // W in LDS -> VGPR ~44 -> 32 waves/CU bin; 2048 blocks fills it.
    fused_kernel<1><<<2048, 256, 0, stream>>>(
        tA, tB, W + 1 * D * D, b + 1 * D, cv, row_ptr, out);
    fused_kernel<0><<<2048, 256, 0, stream>>>(
        tB, tA, W + 2 * D * D, b + 2 * D, cv, row_ptr, out);
    fused_kernel<0><<<2048, 256, 0, stream>>>(
        tA, tB, W + 3 * D * D, b + 3 * D, cv, row_ptr, out);

    // head 4: spmm only (R7 structure, 1 row/wave)
    spmm_kernel<<<(N_NODES * 64 + 255) / 256, 256, 0, stream>>>(
        tB, cv, row_ptr, out);
}